// Round 8
// baseline (411.189 us; speedup 1.0000x reference)
//
#include <hip/hip_runtime.h>
#include <hip/hip_cooperative_groups.h>

namespace cg = cooperative_groups;

#define N_NODESC 100000
#define N_EDGESC 1600000
#define BN_EPSC 1e-5f
#define NBUCK 1024              // coarse buckets (dst>>7), 782 used
#define SBLK 256                // cooperative grid blocks
#define EPB (N_EDGESC / SBLK)   // 6250 edges per block
#define HN (NBUCK * SBLK)       // 262144 hist entries
#define MT 128                  // nodes per MLP block

// ---------------------------------------------------------------------------
// K_pre (cooperative, 256 blocks x 1024): the whole CSR build in one launch.
//  p1: coarse histogram (LDS) + bf16 cast of x (batched loads for ILP)
//  p2: per-chunk exclusive scan (4 chunks/block; chunk == bucket)
//  p3: block 0 scans the 1024 bucket totals
//  p4: coarse scatter into tmp (contiguous (bucket,block) runs)
//  p5: per-bucket node-sort into packed + global CSR off (4 buckets/block)
// ---------------------------------------------------------------------------
__global__ __launch_bounds__(1024) void k_pre(
    const int* __restrict__ ei, const int* __restrict__ ea,
    const float* __restrict__ x, uint2* __restrict__ xh4,
    int* __restrict__ Hm, int* __restrict__ Sloc,
    int* __restrict__ bsum, int* __restrict__ bsumx,
    int* __restrict__ off, int* __restrict__ tmp, int* __restrict__ packed)
{
    cg::grid_group grid = cg::this_grid();
    __shared__ int h[NBUCK];
    __shared__ int wsum[4][4];
    const int t = threadIdx.x;
    const int k = blockIdx.x;
    const int base = k * EPB;

    // ---- phase 1: histogram + cast -------------------------------------
    h[t] = 0;
    __syncthreads();
    #pragma unroll
    for (int i = 0; i < 7; i++) {
        const int e = base + i * 1024 + t;
        if (e < base + EPB) atomicAdd(&h[ei[N_EDGESC + e] >> 7], 1);
    }
    {   // cast 1.6M float4 -> bf16x4; 7 batched independent loads per thread
        const float4* x4 = (const float4*)x;
        const int g = k * 1024 + t;
        float4 v[7];
        #pragma unroll
        for (int i = 0; i < 7; i++) {
            const int idx = g + i * (SBLK * 1024);
            if (idx < N_NODESC * 16) v[i] = x4[idx];
        }
        #pragma unroll
        for (int i = 0; i < 7; i++) {
            const int idx = g + i * (SBLK * 1024);
            if (idx < N_NODESC * 16) {
                unsigned int a = __float_as_uint(v[i].x);
                unsigned int b = __float_as_uint(v[i].y);
                unsigned int c = __float_as_uint(v[i].z);
                unsigned int d = __float_as_uint(v[i].w);
                a = (a + 0x7FFFu + ((a >> 16) & 1u)) >> 16;
                b = (b + 0x7FFFu + ((b >> 16) & 1u)) >> 16;
                c = (c + 0x7FFFu + ((c >> 16) & 1u)) >> 16;
                d = (d + 0x7FFFu + ((d >> 16) & 1u)) >> 16;
                xh4[idx] = make_uint2(a | (b << 16), c | (d << 16));
            }
        }
    }
    __syncthreads();
    Hm[t * SBLK + k] = h[t];
    if (k == 0 && t == 0) off[N_NODESC] = N_EDGESC;
    grid.sync();

    // ---- phase 2: scan 4 chunks of 256 (chunk == bucket) ---------------
    {
        const int grp = t >> 8;
        const int lt = t & 255;
        const int lane = t & 63;
        const int wid = (t >> 6) & 3;
        const int chunk = k * 4 + grp;
        const int i = chunk * 256 + lt;
        const int v = Hm[i];
        int inc = v;
        #pragma unroll
        for (int d = 1; d < 64; d <<= 1) {
            const int u = __shfl_up(inc, d);
            if (lane >= d) inc += u;
        }
        if (lane == 63) wsum[grp][wid] = inc;
        __syncthreads();
        int add = 0;
        #pragma unroll
        for (int w = 0; w < 3; w++) if (w < wid) add += wsum[grp][w];
        Sloc[i] = inc - v + add;
        if (lt == 255) bsum[chunk] = add + inc;
    }
    grid.sync();

    // ---- phase 3: block 0 scans the 1024 bucket totals -----------------
    if (k == 0) {
        const int v = bsum[t];
        h[t] = v;
        __syncthreads();
        for (int d = 1; d < 1024; d <<= 1) {
            const int u = (t >= d) ? h[t - d] : 0;
            __syncthreads();
            h[t] += u;
            __syncthreads();
        }
        bsumx[t] = h[t] - v;
    }
    grid.sync();

    // ---- phase 4: coarse scatter ---------------------------------------
    h[t] = Sloc[t * SBLK + k] + bsumx[t];   // h = lcur
    __syncthreads();
    #pragma unroll
    for (int i = 0; i < 7; i++) {
        const int e = base + i * 1024 + t;
        if (e < base + EPB) {
            const int src = ei[e];
            const int dst = ei[N_EDGESC + e];
            const int a = ea[e];
            const int pos = atomicAdd(&h[dst >> 7], 1);
            tmp[pos] = src | (a << 17) | ((dst & 127) << 19);
        }
    }
    grid.sync();

    // ---- phase 5: per-bucket CSR finalize (4 buckets/block) ------------
    for (int bb = 0; bb < 4; bb++) {
        const int b = k * 4 + bb;
        __syncthreads();                    // protect h reuse
        if (t < 128) h[t] = 0;              // cnt = h[0:128], cur = h[128:256]
        __syncthreads();
        const int start = Sloc[b * 256] + bsumx[b];
        const int end = (b == NBUCK - 1) ? N_EDGESC
                                         : (Sloc[(b + 1) * 256] + bsumx[b + 1]);
        for (int e = start + t; e < end; e += 1024)
            atomicAdd(&h[(tmp[e] >> 19) & 127], 1);
        __syncthreads();
        if (t < 64) {
            const int lane = t;
            const int v0 = h[lane];
            const int v1 = h[64 + lane];
            int i0 = v0, i1 = v1;
            #pragma unroll
            for (int d = 1; d < 64; d <<= 1) {
                const int u0 = __shfl_up(i0, d);
                const int u1 = __shfl_up(i1, d);
                if (lane >= d) { i0 += u0; i1 += u1; }
            }
            const int tot0 = __shfl(i0, 63);
            const int o0 = start + i0 - v0;
            const int o1 = start + tot0 + i1 - v1;
            h[128 + lane] = o0;
            h[192 + lane] = o1;
            const int n0 = b * 128 + lane;
            if (n0 < N_NODESC) off[n0] = o0;
            if (n0 + 64 < N_NODESC) off[n0 + 64] = o1;
        }
        __syncthreads();
        for (int e = start + t; e < end; e += 1024) {
            const int p = tmp[e];
            const int pos = atomicAdd(&h[128 + ((p >> 19) & 127)], 1);
            packed[pos] = p & 0x7FFFF;
        }
    }
}

// ---------------------------------------------------------------------------
// K_agg: per-node register accumulation; bf16 x rows (128B), f32 accumulate.
// ---------------------------------------------------------------------------
__global__ __launch_bounds__(256) void k_agg(
    const ushort* __restrict__ xh, const float* __restrict__ emb,
    const int* __restrict__ off, const int* __restrict__ packed,
    float* __restrict__ agg)
{
    const int t = threadIdx.x;
    const int q = t & 15;
    const int node = blockIdx.x * 16 + (t >> 4);
    const int start = off[node];
    const int end = off[node + 1];
    const ushort4* xv4 = (const ushort4*)xh;
    const float4* e4 = (const float4*)emb;
    float4 acc = make_float4(0.f, 0.f, 0.f, 0.f);
    int e = start;
    for (; e + 2 <= end; e += 2) {
        const int p0 = packed[e];
        const int p1 = packed[e + 1];
        const ushort4 u0 = xv4[(size_t)(p0 & 0x1FFFF) * 16 + q];
        const ushort4 u1 = xv4[(size_t)(p1 & 0x1FFFF) * 16 + q];
        const float4 t0 = e4[((p0 >> 17) & 3) * 16 + q];
        const float4 t1 = e4[((p1 >> 17) & 3) * 16 + q];
        acc.x += fmaxf(__uint_as_float((unsigned int)u0.x << 16) + t0.x, 0.f)
               + fmaxf(__uint_as_float((unsigned int)u1.x << 16) + t1.x, 0.f);
        acc.y += fmaxf(__uint_as_float((unsigned int)u0.y << 16) + t0.y, 0.f)
               + fmaxf(__uint_as_float((unsigned int)u1.y << 16) + t1.y, 0.f);
        acc.z += fmaxf(__uint_as_float((unsigned int)u0.z << 16) + t0.z, 0.f)
               + fmaxf(__uint_as_float((unsigned int)u1.z << 16) + t1.z, 0.f);
        acc.w += fmaxf(__uint_as_float((unsigned int)u0.w << 16) + t0.w, 0.f)
               + fmaxf(__uint_as_float((unsigned int)u1.w << 16) + t1.w, 0.f);
    }
    if (e < end) {
        const int p0 = packed[e];
        const ushort4 u0 = xv4[(size_t)(p0 & 0x1FFFF) * 16 + q];
        const float4 t0 = e4[((p0 >> 17) & 3) * 16 + q];
        acc.x += fmaxf(__uint_as_float((unsigned int)u0.x << 16) + t0.x, 0.f);
        acc.y += fmaxf(__uint_as_float((unsigned int)u0.y << 16) + t0.y, 0.f);
        acc.z += fmaxf(__uint_as_float((unsigned int)u0.z << 16) + t0.z, 0.f);
        acc.w += fmaxf(__uint_as_float((unsigned int)u0.w << 16) + t0.w, 0.f);
    }
    ((float4*)agg)[(size_t)node * 16 + q] = acc;
}

// ---------------------------------------------------------------------------
// K_mlp1: hbuf := ((1+eps)*x + hbuf) @ W1 + b1 ; BN column sums.
// 128 nodes/block, 4 nodes x 8 cols per thread.
// ---------------------------------------------------------------------------
__global__ __launch_bounds__(256) void k_mlp1(
    const float* __restrict__ x, float* hbuf,
    const float* __restrict__ W1, const float* __restrict__ b1,
    const float* __restrict__ epsp,
    float* __restrict__ cs, float* __restrict__ css)
{
    __shared__ float lin[MT][68];
    __shared__ float lW[4096];
    __shared__ float redS[4][64];
    __shared__ float redQ[4][64];
    const int t = threadIdx.x;
    const int nbase = blockIdx.x * MT;
    const float sc1 = 1.0f + epsp[0];

    {
        const float4* W4 = (const float4*)W1;
        float4* lW4 = (float4*)lW;
        #pragma unroll
        for (int i = 0; i < 4; i++) lW4[i * 256 + t] = W4[i * 256 + t];
    }
    {
        const float4* x4 = (const float4*)x;
        const float4* a4 = (const float4*)hbuf;
        #pragma unroll
        for (int i = 0; i < 8; i++) {
            const int fidx = i * 256 + t;
            const int row = fidx >> 4;
            const int q = fidx & 15;
            const int n = nbase + row;
            float4 v = make_float4(0.f, 0.f, 0.f, 0.f);
            if (n < N_NODESC) {
                const float4 xv = x4[(size_t)n * 16 + q];
                const float4 av = a4[(size_t)n * 16 + q];
                v.x = fmaf(sc1, xv.x, av.x);
                v.y = fmaf(sc1, xv.y, av.y);
                v.z = fmaf(sc1, xv.z, av.z);
                v.w = fmaf(sc1, xv.w, av.w);
            }
            *(float4*)&lin[row][q * 4] = v;
        }
    }
    __syncthreads();

    const int g = t & 7;
    const int r0 = t >> 3;
    const float4* lW4 = (const float4*)lW;
    const float4* b4 = (const float4*)b1;
    const float4 bb0 = b4[g * 2 + 0];
    const float4 bb1 = b4[g * 2 + 1];
    float4 a00 = bb0, a01 = bb1, a10 = bb0, a11 = bb1;
    float4 a20 = bb0, a21 = bb1, a30 = bb0, a31 = bb1;
    for (int k = 0; k < 64; k++) {
        const float v0 = lin[r0][k];
        const float v1 = lin[r0 + 32][k];
        const float v2 = lin[r0 + 64][k];
        const float v3 = lin[r0 + 96][k];
        const float4 w0 = lW4[k * 16 + g * 2 + 0];
        const float4 w1 = lW4[k * 16 + g * 2 + 1];
        a00.x = fmaf(v0, w0.x, a00.x); a00.y = fmaf(v0, w0.y, a00.y);
        a00.z = fmaf(v0, w0.z, a00.z); a00.w = fmaf(v0, w0.w, a00.w);
        a01.x = fmaf(v0, w1.x, a01.x); a01.y = fmaf(v0, w1.y, a01.y);
        a01.z = fmaf(v0, w1.z, a01.z); a01.w = fmaf(v0, w1.w, a01.w);
        a10.x = fmaf(v1, w0.x, a10.x); a10.y = fmaf(v1, w0.y, a10.y);
        a10.z = fmaf(v1, w0.z, a10.z); a10.w = fmaf(v1, w0.w, a10.w);
        a11.x = fmaf(v1, w1.x, a11.x); a11.y = fmaf(v1, w1.y, a11.y);
        a11.z = fmaf(v1, w1.z, a11.z); a11.w = fmaf(v1, w1.w, a11.w);
        a20.x = fmaf(v2, w0.x, a20.x); a20.y = fmaf(v2, w0.y, a20.y);
        a20.z = fmaf(v2, w0.z, a20.z); a20.w = fmaf(v2, w0.w, a20.w);
        a21.x = fmaf(v2, w1.x, a21.x); a21.y = fmaf(v2, w1.y, a21.y);
        a21.z = fmaf(v2, w1.z, a21.z); a21.w = fmaf(v2, w1.w, a21.w);
        a30.x = fmaf(v3, w0.x, a30.x); a30.y = fmaf(v3, w0.y, a30.y);
        a30.z = fmaf(v3, w0.z, a30.z); a30.w = fmaf(v3, w0.w, a30.w);
        a31.x = fmaf(v3, w1.x, a31.x); a31.y = fmaf(v3, w1.y, a31.y);
        a31.z = fmaf(v3, w1.z, a31.z); a31.w = fmaf(v3, w1.w, a31.w);
    }

    float4 A0[4] = {a00, a10, a20, a30};
    float4 A1[4] = {a01, a11, a21, a31};
    float4* h4 = (float4*)hbuf;
    float msk[4];
    #pragma unroll
    for (int j = 0; j < 4; j++) {
        const int n = nbase + r0 + 32 * j;
        msk[j] = (n < N_NODESC) ? 1.0f : 0.0f;
        if (n < N_NODESC) {
            h4[(size_t)n * 16 + g * 2 + 0] = A0[j];
            h4[(size_t)n * 16 + g * 2 + 1] = A1[j];
        }
    }

    float vs[8], vq[8];
    #pragma unroll
    for (int c = 0; c < 8; c++) { vs[c] = 0.f; vq[c] = 0.f; }
    #pragma unroll
    for (int j = 0; j < 4; j++) {
        const float e0[8] = {A0[j].x, A0[j].y, A0[j].z, A0[j].w,
                             A1[j].x, A1[j].y, A1[j].z, A1[j].w};
        #pragma unroll
        for (int c = 0; c < 8; c++) {
            const float v = e0[c] * msk[j];
            vs[c] += v;
            vq[c] += v * e0[c];
        }
    }
    #pragma unroll
    for (int o = 8; o < 64; o <<= 1) {
        #pragma unroll
        for (int c = 0; c < 8; c++) {
            vs[c] += __shfl_xor(vs[c], o);
            vq[c] += __shfl_xor(vq[c], o);
        }
    }
    const int lane = t & 63;
    const int w = t >> 6;
    if (lane < 8) {
        #pragma unroll
        for (int c = 0; c < 8; c++) {
            redS[w][lane * 8 + c] = vs[c];
            redQ[w][lane * 8 + c] = vq[c];
        }
    }
    __syncthreads();
    if (t < 64) {
        const float s = redS[0][t] + redS[1][t] + redS[2][t] + redS[3][t];
        const float qq = redQ[0][t] + redQ[1][t] + redQ[2][t] + redQ[3][t];
        unsafeAtomicAdd(&cs[t], s);
        unsafeAtomicAdd(&css[t], qq);
    }
}

// ---------------------------------------------------------------------------
// K_mlp2: out = relu(BN(h1)) @ W2 + b2.  h1 aliases out; LDS-staged.
// ---------------------------------------------------------------------------
__global__ __launch_bounds__(256) void k_mlp2(
    const float* h1, const float* __restrict__ W2, const float* __restrict__ b2,
    const float* __restrict__ gamma, const float* __restrict__ beta,
    const float* __restrict__ cs, const float* __restrict__ css,
    float* out)
{
    __shared__ float lin[MT][68];
    __shared__ float lW[4096];
    __shared__ float scl[64];
    __shared__ float sft[64];
    const int t = threadIdx.x;
    const int nbase = blockIdx.x * MT;

    if (t < 64) {
        const float inv = 1.0f / (float)N_NODESC;
        const float mu = cs[t] * inv;
        const float var = css[t] * inv - mu * mu;
        const float rs = rsqrtf(var + BN_EPSC);
        const float s = rs * gamma[t];
        scl[t] = s;
        sft[t] = fmaf(-mu, s, beta[t]);
    }
    {
        const float4* W4 = (const float4*)W2;
        float4* lW4 = (float4*)lW;
        #pragma unroll
        for (int i = 0; i < 4; i++) lW4[i * 256 + t] = W4[i * 256 + t];
    }
    __syncthreads();
    {
        const float4* h4 = (const float4*)h1;
        #pragma unroll
        for (int i = 0; i < 8; i++) {
            const int fidx = i * 256 + t;
            const int row = fidx >> 4;
            const int q = fidx & 15;
            const int n = nbase + row;
            float4 v = make_float4(0.f, 0.f, 0.f, 0.f);
            if (n < N_NODESC) {
                const float4 h = h4[(size_t)n * 16 + q];
                const int c = q * 4;
                v.x = fmaxf(fmaf(h.x, scl[c + 0], sft[c + 0]), 0.f);
                v.y = fmaxf(fmaf(h.y, scl[c + 1], sft[c + 1]), 0.f);
                v.z = fmaxf(fmaf(h.z, scl[c + 2], sft[c + 2]), 0.f);
                v.w = fmaxf(fmaf(h.w, scl[c + 3], sft[c + 3]), 0.f);
            }
            *(float4*)&lin[row][q * 4] = v;
        }
    }
    __syncthreads();

    const int g = t & 7;
    const int r0 = t >> 3;
    const float4* lW4 = (const float4*)lW;
    const float4* b4 = (const float4*)b2;
    const float4 bb0 = b4[g * 2 + 0];
    const float4 bb1 = b4[g * 2 + 1];
    float4 a00 = bb0, a01 = bb1, a10 = bb0, a11 = bb1;
    float4 a20 = bb0, a21 = bb1, a30 = bb0, a31 = bb1;
    for (int k = 0; k < 64; k++) {
        const float v0 = lin[r0][k];
        const float v1 = lin[r0 + 32][k];
        const float v2 = lin[r0 + 64][k];
        const float v3 = lin[r0 + 96][k];
        const float4 w0 = lW4[k * 16 + g * 2 + 0];
        const float4 w1 = lW4[k * 16 + g * 2 + 1];
        a00.x = fmaf(v0, w0.x, a00.x); a00.y = fmaf(v0, w0.y, a00.y);
        a00.z = fmaf(v0, w0.z, a00.z); a00.w = fmaf(v0, w0.w, a00.w);
        a01.x = fmaf(v0, w1.x, a01.x); a01.y = fmaf(v0, w1.y, a01.y);
        a01.z = fmaf(v0, w1.z, a01.z); a01.w = fmaf(v0, w1.w, a01.w);
        a10.x = fmaf(v1, w0.x, a10.x); a10.y = fmaf(v1, w0.y, a10.y);
        a10.z = fmaf(v1, w0.z, a10.z); a10.w = fmaf(v1, w0.w, a10.w);
        a11.x = fmaf(v1, w1.x, a11.x); a11.y = fmaf(v1, w1.y, a11.y);
        a11.z = fmaf(v1, w1.z, a11.z); a11.w = fmaf(v1, w1.w, a11.w);
        a20.x = fmaf(v2, w0.x, a20.x); a20.y = fmaf(v2, w0.y, a20.y);
        a20.z = fmaf(v2, w0.z, a20.z); a20.w = fmaf(v2, w0.w, a20.w);
        a21.x = fmaf(v2, w1.x, a21.x); a21.y = fmaf(v2, w1.y, a21.y);
        a21.z = fmaf(v2, w1.z, a21.z); a21.w = fmaf(v2, w1.w, a21.w);
        a30.x = fmaf(v3, w0.x, a30.x); a30.y = fmaf(v3, w0.y, a30.y);
        a30.z = fmaf(v3, w0.z, a30.z); a30.w = fmaf(v3, w0.w, a30.w);
        a31.x = fmaf(v3, w1.x, a31.x); a31.y = fmaf(v3, w1.y, a31.y);
        a31.z = fmaf(v3, w1.z, a31.z); a31.w = fmaf(v3, w1.w, a31.w);
    }
    const float4 A0[4] = {a00, a10, a20, a30};
    const float4 A1[4] = {a01, a11, a21, a31};
    float4* o4 = (float4*)out;
    #pragma unroll
    for (int j = 0; j < 4; j++) {
        const int n = nbase + r0 + 32 * j;
        if (n < N_NODESC) {
            o4[(size_t)n * 16 + g * 2 + 0] = A0[j];
            o4[(size_t)n * 16 + g * 2 + 1] = A1[j];
        }
    }
}

// ---------------------------------------------------------------------------
extern "C" void kernel_launch(void* const* d_in, const int* in_sizes, int n_in,
                              void* d_out, int out_size, void* d_ws, size_t ws_size,
                              hipStream_t stream) {
    const float* x     = (const float*)d_in[0];
    const float* emb   = (const float*)d_in[1];
    const float* eps   = (const float*)d_in[2];
    const float* W1    = (const float*)d_in[3];
    const float* b1    = (const float*)d_in[4];
    const float* gamma = (const float*)d_in[5];
    const float* beta  = (const float*)d_in[6];
    const float* W2    = (const float*)d_in[7];
    const float* b2    = (const float*)d_in[8];
    const int*   ei    = (const int*)d_in[9];
    const int*   ea    = (const int*)d_in[10];
    float* out = (float*)d_out;

    // ws: [cs 64][css 64][Hm HN][Sloc HN][bsum 1024][bsumx 1024]
    //     [off N+1][tmp E][packed E][xh N*64 bf16]   (~29 MB)
    float* ws    = (float*)d_ws;
    float* cs    = ws;
    float* css   = ws + 64;
    int*   Hm    = (int*)(ws + 128);
    int*   Sloc  = Hm + HN;
    int*   bsum  = Sloc + HN;
    int*   bsumx = bsum + 1024;
    int*   off   = bsumx + 1024;
    int*   tmp   = off + N_NODESC + 1;
    int*   packed= tmp + N_EDGESC;
    ushort* xh   = (ushort*)(packed + N_EDGESC);

    hipMemsetAsync(d_ws, 0, 128 * sizeof(float), stream);  // cs/css only

    {
        uint2* xh4 = (uint2*)xh;
        void* args[] = {(void*)&ei, (void*)&ea, (void*)&x, (void*)&xh4,
                        (void*)&Hm, (void*)&Sloc, (void*)&bsum, (void*)&bsumx,
                        (void*)&off, (void*)&tmp, (void*)&packed};
        hipLaunchCooperativeKernel((void*)k_pre, dim3(SBLK), dim3(1024),
                                   args, 0, stream);
    }

    k_agg<<<N_NODESC / 16, 256, 0, stream>>>(xh, emb, off, packed, out);

    const int nblk = (N_NODESC + MT - 1) / MT;   // 782
    k_mlp1<<<nblk, 256, 0, stream>>>(x, out, W1, b1, eps, cs, css);
    k_mlp2<<<nblk, 256, 0, stream>>>(out, W2, b2, gamma, beta, cs, css, out);
}

// Round 9
// 248.436 us; speedup vs baseline: 1.6551x; 1.6551x over previous
//
#include <hip/hip_runtime.h>

#define N_NODESC 100000
#define N_EDGESC 1600000
#define BN_EPSC 1e-5f
#define NBUCK 1024              // coarse buckets (dst>>7), 782 used
#define SBLK 256                // scatter/hist blocks
#define EPB (N_EDGESC / SBLK)   // 6250 edges per block
#define HN (NBUCK * SBLK)       // 262144 hist entries
#define MT 128                  // nodes per MLP block
#define BCAP 4608               // LDS edge capacity per bucket (mean 2048, sigma 45)

// ---------------------------------------------------------------------------
// K_hist_cast: coarse histogram (Hm bucket-major) + batched bf16 cast of x
// + zero cs/css (block 0).  Cast uses 7 independent loads for ILP.
// ---------------------------------------------------------------------------
__global__ __launch_bounds__(1024) void k_hist_cast(
    const int* __restrict__ ei, int* __restrict__ Hm,
    const float* __restrict__ x, uint2* __restrict__ xh4,
    float* __restrict__ cs0)
{
    __shared__ int h[NBUCK];
    const int t = threadIdx.x;
    const int k = blockIdx.x;
    h[t] = 0;
    __syncthreads();
    const int base = k * EPB;
    #pragma unroll
    for (int i = 0; i < 7; i++) {
        const int e = base + i * 1024 + t;
        if (e < base + EPB) atomicAdd(&h[ei[N_EDGESC + e] >> 7], 1);
    }
    {   // cast 1.6M float4 -> bf16x4 (RNE), batched
        const float4* x4 = (const float4*)x;
        const int g = k * 1024 + t;
        float4 v[7];
        bool m[7];
        #pragma unroll
        for (int i = 0; i < 7; i++) {
            const int idx = g + i * (SBLK * 1024);
            m[i] = (idx < N_NODESC * 16);
            if (m[i]) v[i] = x4[idx];
        }
        #pragma unroll
        for (int i = 0; i < 7; i++) {
            if (m[i]) {
                const int idx = g + i * (SBLK * 1024);
                unsigned int a = __float_as_uint(v[i].x);
                unsigned int b = __float_as_uint(v[i].y);
                unsigned int c = __float_as_uint(v[i].z);
                unsigned int d = __float_as_uint(v[i].w);
                a = (a + 0x7FFFu + ((a >> 16) & 1u)) >> 16;
                b = (b + 0x7FFFu + ((b >> 16) & 1u)) >> 16;
                c = (c + 0x7FFFu + ((c >> 16) & 1u)) >> 16;
                d = (d + 0x7FFFu + ((d >> 16) & 1u)) >> 16;
                xh4[idx] = make_uint2(a | (b << 16), c | (d << 16));
            }
        }
    }
    if (k == 0 && t < 128) cs0[t] = 0.f;   // zero cs+css (contiguous)
    __syncthreads();
    Hm[t * SBLK + k] = h[t];
}

// ---------------------------------------------------------------------------
// K_scan1: per-bucket exclusive scan of 256 counts + bucket totals.
// ---------------------------------------------------------------------------
__global__ __launch_bounds__(256) void k_scan1(
    const int* __restrict__ in, int* __restrict__ local, int* __restrict__ bsum)
{
    __shared__ int wsum[4];
    const int t = threadIdx.x;
    const int i = blockIdx.x * 256 + t;
    const int lane = t & 63;
    const int wid = t >> 6;
    const int v = in[i];
    int inc = v;
    #pragma unroll
    for (int d = 1; d < 64; d <<= 1) {
        const int u = __shfl_up(inc, d);
        if (lane >= d) inc += u;
    }
    if (lane == 63) wsum[wid] = inc;
    __syncthreads();
    int add = 0;
    #pragma unroll
    for (int w = 0; w < 3; w++) if (w < wid) add += wsum[w];
    local[i] = inc - v + add;
    if (t == 255) bsum[blockIdx.x] = add + inc;
}

// ---------------------------------------------------------------------------
// K_scatter2: edges -> coarse buckets; bucket prefix computed locally from
// bsum (LDS Hillis-Steele).  tmp = src(17b) | attr<<17(2b) | (dst&127)<<19.
// ---------------------------------------------------------------------------
__global__ __launch_bounds__(1024) void k_scatter2(
    const int* __restrict__ ei, const int* __restrict__ ea,
    const int* __restrict__ Sloc, const int* __restrict__ bsum,
    int* __restrict__ tmp)
{
    __shared__ int s[NBUCK];
    __shared__ int lcur[NBUCK];
    const int t = threadIdx.x;
    const int k = blockIdx.x;
    const int v = bsum[t];
    s[t] = v;
    __syncthreads();
    for (int d = 1; d < 1024; d <<= 1) {
        const int u = (t >= d) ? s[t - d] : 0;
        __syncthreads();
        s[t] += u;
        __syncthreads();
    }
    lcur[t] = Sloc[t * SBLK + k] + s[t] - v;   // bucketStart + within-bucket off
    __syncthreads();
    const int base = k * EPB;
    #pragma unroll
    for (int i = 0; i < 7; i++) {
        const int e = base + i * 1024 + t;
        if (e < base + EPB) {
            const int src = ei[e];
            const int dst = ei[N_EDGESC + e];
            const int a = ea[e];
            const int pos = atomicAdd(&lcur[dst >> 7], 1);
            tmp[pos] = src | (a << 17) | ((dst & 127) << 19);
        }
    }
}

// ---------------------------------------------------------------------------
// K_aggf: fused per-bucket node-sort (LDS) + register aggregation.
// One block per bucket: count 128 node degrees, scan, place edges into
// packedL (LDS), then 16 groups x 16 lanes accumulate 8 nodes each.
// ---------------------------------------------------------------------------
__global__ __launch_bounds__(256) void k_aggf(
    const ushort* __restrict__ xh, const float* __restrict__ emb,
    const int* __restrict__ bsum, const int* __restrict__ tmp,
    float* __restrict__ agg)
{
    __shared__ int packedL[BCAP];
    __shared__ int cnt[128];
    __shared__ int cst[128];
    __shared__ int cur[128];
    __shared__ int red[4];
    const int t = threadIdx.x;
    const int b = blockIdx.x;

    // start = prefix(bsum)[b] via masked block reduction
    int part = 0;
    #pragma unroll
    for (int j = 0; j < 4; j++) {
        const int idx = t * 4 + j;
        const int bv = bsum[idx];
        if (idx < b) part += bv;
    }
    #pragma unroll
    for (int o = 1; o < 64; o <<= 1) part += __shfl_xor(part, o);
    if ((t & 63) == 0) red[t >> 6] = part;
    if (t < 128) cnt[t] = 0;
    __syncthreads();
    const int start = red[0] + red[1] + red[2] + red[3];
    const int cntb = bsum[b];

    // pass 1: per-node counts
    for (int e = t; e < cntb; e += 256)
        atomicAdd(&cnt[(tmp[start + e] >> 19) & 127], 1);
    __syncthreads();
    // scan 128 counts (two 64-lane halves)
    if (t < 64) {
        const int lane = t;
        const int v0 = cnt[lane];
        const int v1 = cnt[64 + lane];
        int i0 = v0, i1 = v1;
        #pragma unroll
        for (int d = 1; d < 64; d <<= 1) {
            const int u0 = __shfl_up(i0, d);
            const int u1 = __shfl_up(i1, d);
            if (lane >= d) { i0 += u0; i1 += u1; }
        }
        const int tot0 = __shfl(i0, 63);
        cst[lane] = i0 - v0;
        cst[64 + lane] = tot0 + i1 - v1;
        cur[lane] = i0 - v0;
        cur[64 + lane] = tot0 + i1 - v1;
    }
    __syncthreads();
    // pass 2: place into LDS, node-sorted
    for (int e = t; e < cntb; e += 256) {
        const int p = tmp[start + e];
        const int pos = atomicAdd(&cur[(p >> 19) & 127], 1);
        if (pos < BCAP) packedL[pos] = p;
    }
    __syncthreads();

    // aggregate: group g -> nodes g*8 .. g*8+7, lane q = feature quarter
    const int g = t >> 4;
    const int q = t & 15;
    const ushort4* xv4 = (const ushort4*)xh;
    const float4* e4 = (const float4*)emb;
    float4* o4 = (float4*)agg;
    for (int j = 0; j < 8; j++) {
        const int nl = g * 8 + j;
        int e = cst[nl];
        const int ee = cur[nl];           // cur == end after pass 2
        float4 acc = make_float4(0.f, 0.f, 0.f, 0.f);
        for (; e + 2 <= ee; e += 2) {
            const int p0 = packedL[e];
            const int p1 = packedL[e + 1];
            const ushort4 u0 = xv4[(size_t)(p0 & 0x1FFFF) * 16 + q];
            const ushort4 u1 = xv4[(size_t)(p1 & 0x1FFFF) * 16 + q];
            const float4 t0 = e4[((p0 >> 17) & 3) * 16 + q];
            const float4 t1 = e4[((p1 >> 17) & 3) * 16 + q];
            acc.x += fmaxf(__uint_as_float((unsigned int)u0.x << 16) + t0.x, 0.f)
                   + fmaxf(__uint_as_float((unsigned int)u1.x << 16) + t1.x, 0.f);
            acc.y += fmaxf(__uint_as_float((unsigned int)u0.y << 16) + t0.y, 0.f)
                   + fmaxf(__uint_as_float((unsigned int)u1.y << 16) + t1.y, 0.f);
            acc.z += fmaxf(__uint_as_float((unsigned int)u0.z << 16) + t0.z, 0.f)
                   + fmaxf(__uint_as_float((unsigned int)u1.z << 16) + t1.z, 0.f);
            acc.w += fmaxf(__uint_as_float((unsigned int)u0.w << 16) + t0.w, 0.f)
                   + fmaxf(__uint_as_float((unsigned int)u1.w << 16) + t1.w, 0.f);
        }
        if (e < ee) {
            const int p0 = packedL[e];
            const ushort4 u0 = xv4[(size_t)(p0 & 0x1FFFF) * 16 + q];
            const float4 t0 = e4[((p0 >> 17) & 3) * 16 + q];
            acc.x += fmaxf(__uint_as_float((unsigned int)u0.x << 16) + t0.x, 0.f);
            acc.y += fmaxf(__uint_as_float((unsigned int)u0.y << 16) + t0.y, 0.f);
            acc.z += fmaxf(__uint_as_float((unsigned int)u0.z << 16) + t0.z, 0.f);
            acc.w += fmaxf(__uint_as_float((unsigned int)u0.w << 16) + t0.w, 0.f);
        }
        const int n = b * 128 + nl;
        if (n < N_NODESC) o4[(size_t)n * 16 + q] = acc;
    }
}

// ---------------------------------------------------------------------------
// K_mlp1: hbuf := ((1+eps)*x + hbuf) @ W1 + b1 ; BN column sums.
// 128 nodes/block, 4 nodes x 8 cols per thread.
// ---------------------------------------------------------------------------
__global__ __launch_bounds__(256) void k_mlp1(
    const float* __restrict__ x, float* hbuf,
    const float* __restrict__ W1, const float* __restrict__ b1,
    const float* __restrict__ epsp,
    float* __restrict__ cs, float* __restrict__ css)
{
    __shared__ float lin[MT][68];
    __shared__ float lW[4096];
    __shared__ float redS[4][64];
    __shared__ float redQ[4][64];
    const int t = threadIdx.x;
    const int nbase = blockIdx.x * MT;
    const float sc1 = 1.0f + epsp[0];

    {
        const float4* W4 = (const float4*)W1;
        float4* lW4 = (float4*)lW;
        #pragma unroll
        for (int i = 0; i < 4; i++) lW4[i * 256 + t] = W4[i * 256 + t];
    }
    {
        const float4* x4 = (const float4*)x;
        const float4* a4 = (const float4*)hbuf;
        #pragma unroll
        for (int i = 0; i < 8; i++) {
            const int fidx = i * 256 + t;
            const int row = fidx >> 4;
            const int q = fidx & 15;
            const int n = nbase + row;
            float4 v = make_float4(0.f, 0.f, 0.f, 0.f);
            if (n < N_NODESC) {
                const float4 xv = x4[(size_t)n * 16 + q];
                const float4 av = a4[(size_t)n * 16 + q];
                v.x = fmaf(sc1, xv.x, av.x);
                v.y = fmaf(sc1, xv.y, av.y);
                v.z = fmaf(sc1, xv.z, av.z);
                v.w = fmaf(sc1, xv.w, av.w);
            }
            *(float4*)&lin[row][q * 4] = v;
        }
    }
    __syncthreads();

    const int g = t & 7;
    const int r0 = t >> 3;
    const float4* lW4 = (const float4*)lW;
    const float4* b4 = (const float4*)b1;
    const float4 bb0 = b4[g * 2 + 0];
    const float4 bb1 = b4[g * 2 + 1];
    float4 a00 = bb0, a01 = bb1, a10 = bb0, a11 = bb1;
    float4 a20 = bb0, a21 = bb1, a30 = bb0, a31 = bb1;
    for (int k = 0; k < 64; k++) {
        const float v0 = lin[r0][k];
        const float v1 = lin[r0 + 32][k];
        const float v2 = lin[r0 + 64][k];
        const float v3 = lin[r0 + 96][k];
        const float4 w0 = lW4[k * 16 + g * 2 + 0];
        const float4 w1 = lW4[k * 16 + g * 2 + 1];
        a00.x = fmaf(v0, w0.x, a00.x); a00.y = fmaf(v0, w0.y, a00.y);
        a00.z = fmaf(v0, w0.z, a00.z); a00.w = fmaf(v0, w0.w, a00.w);
        a01.x = fmaf(v0, w1.x, a01.x); a01.y = fmaf(v0, w1.y, a01.y);
        a01.z = fmaf(v0, w1.z, a01.z); a01.w = fmaf(v0, w1.w, a01.w);
        a10.x = fmaf(v1, w0.x, a10.x); a10.y = fmaf(v1, w0.y, a10.y);
        a10.z = fmaf(v1, w0.z, a10.z); a10.w = fmaf(v1, w0.w, a10.w);
        a11.x = fmaf(v1, w1.x, a11.x); a11.y = fmaf(v1, w1.y, a11.y);
        a11.z = fmaf(v1, w1.z, a11.z); a11.w = fmaf(v1, w1.w, a11.w);
        a20.x = fmaf(v2, w0.x, a20.x); a20.y = fmaf(v2, w0.y, a20.y);
        a20.z = fmaf(v2, w0.z, a20.z); a20.w = fmaf(v2, w0.w, a20.w);
        a21.x = fmaf(v2, w1.x, a21.x); a21.y = fmaf(v2, w1.y, a21.y);
        a21.z = fmaf(v2, w1.z, a21.z); a21.w = fmaf(v2, w1.w, a21.w);
        a30.x = fmaf(v3, w0.x, a30.x); a30.y = fmaf(v3, w0.y, a30.y);
        a30.z = fmaf(v3, w0.z, a30.z); a30.w = fmaf(v3, w0.w, a30.w);
        a31.x = fmaf(v3, w1.x, a31.x); a31.y = fmaf(v3, w1.y, a31.y);
        a31.z = fmaf(v3, w1.z, a31.z); a31.w = fmaf(v3, w1.w, a31.w);
    }

    float4 A0[4] = {a00, a10, a20, a30};
    float4 A1[4] = {a01, a11, a21, a31};
    float4* h4 = (float4*)hbuf;
    float msk[4];
    #pragma unroll
    for (int j = 0; j < 4; j++) {
        const int n = nbase + r0 + 32 * j;
        msk[j] = (n < N_NODESC) ? 1.0f : 0.0f;
        if (n < N_NODESC) {
            h4[(size_t)n * 16 + g * 2 + 0] = A0[j];
            h4[(size_t)n * 16 + g * 2 + 1] = A1[j];
        }
    }

    float vs[8], vq[8];
    #pragma unroll
    for (int c = 0; c < 8; c++) { vs[c] = 0.f; vq[c] = 0.f; }
    #pragma unroll
    for (int j = 0; j < 4; j++) {
        const float e0[8] = {A0[j].x, A0[j].y, A0[j].z, A0[j].w,
                             A1[j].x, A1[j].y, A1[j].z, A1[j].w};
        #pragma unroll
        for (int c = 0; c < 8; c++) {
            const float v = e0[c] * msk[j];
            vs[c] += v;
            vq[c] += v * e0[c];
        }
    }
    #pragma unroll
    for (int o = 8; o < 64; o <<= 1) {
        #pragma unroll
        for (int c = 0; c < 8; c++) {
            vs[c] += __shfl_xor(vs[c], o);
            vq[c] += __shfl_xor(vq[c], o);
        }
    }
    const int lane = t & 63;
    const int w = t >> 6;
    if (lane < 8) {
        #pragma unroll
        for (int c = 0; c < 8; c++) {
            redS[w][lane * 8 + c] = vs[c];
            redQ[w][lane * 8 + c] = vq[c];
        }
    }
    __syncthreads();
    if (t < 64) {
        const float s = redS[0][t] + redS[1][t] + redS[2][t] + redS[3][t];
        const float qq = redQ[0][t] + redQ[1][t] + redQ[2][t] + redQ[3][t];
        unsafeAtomicAdd(&cs[t], s);
        unsafeAtomicAdd(&css[t], qq);
    }
}

// ---------------------------------------------------------------------------
// K_mlp2: out = relu(BN(h1)) @ W2 + b2.  h1 aliases out; LDS-staged.
// ---------------------------------------------------------------------------
__global__ __launch_bounds__(256) void k_mlp2(
    const float* h1, const float* __restrict__ W2, const float* __restrict__ b2,
    const float* __restrict__ gamma, const float* __restrict__ beta,
    const float* __restrict__ cs, const float* __restrict__ css,
    float* out)
{
    __shared__ float lin[MT][68];
    __shared__ float lW[4096];
    __shared__ float scl[64];
    __shared__ float sft[64];
    const int t = threadIdx.x;
    const int nbase = blockIdx.x * MT;

    if (t < 64) {
        const float inv = 1.0f / (float)N_NODESC;
        const float mu = cs[t] * inv;
        const float var = css[t] * inv - mu * mu;
        const float rs = rsqrtf(var + BN_EPSC);
        const float s = rs * gamma[t];
        scl[t] = s;
        sft[t] = fmaf(-mu, s, beta[t]);
    }
    {
        const float4* W4 = (const float4*)W2;
        float4* lW4 = (float4*)lW;
        #pragma unroll
        for (int i = 0; i < 4; i++) lW4[i * 256 + t] = W4[i * 256 + t];
    }
    __syncthreads();
    {
        const float4* h4 = (const float4*)h1;
        #pragma unroll
        for (int i = 0; i < 8; i++) {
            const int fidx = i * 256 + t;
            const int row = fidx >> 4;
            const int q = fidx & 15;
            const int n = nbase + row;
            float4 v = make_float4(0.f, 0.f, 0.f, 0.f);
            if (n < N_NODESC) {
                const float4 h = h4[(size_t)n * 16 + q];
                const int c = q * 4;
                v.x = fmaxf(fmaf(h.x, scl[c + 0], sft[c + 0]), 0.f);
                v.y = fmaxf(fmaf(h.y, scl[c + 1], sft[c + 1]), 0.f);
                v.z = fmaxf(fmaf(h.z, scl[c + 2], sft[c + 2]), 0.f);
                v.w = fmaxf(fmaf(h.w, scl[c + 3], sft[c + 3]), 0.f);
            }
            *(float4*)&lin[row][q * 4] = v;
        }
    }
    __syncthreads();

    const int g = t & 7;
    const int r0 = t >> 3;
    const float4* lW4 = (const float4*)lW;
    const float4* b4 = (const float4*)b2;
    const float4 bb0 = b4[g * 2 + 0];
    const float4 bb1 = b4[g * 2 + 1];
    float4 a00 = bb0, a01 = bb1, a10 = bb0, a11 = bb1;
    float4 a20 = bb0, a21 = bb1, a30 = bb0, a31 = bb1;
    for (int k = 0; k < 64; k++) {
        const float v0 = lin[r0][k];
        const float v1 = lin[r0 + 32][k];
        const float v2 = lin[r0 + 64][k];
        const float v3 = lin[r0 + 96][k];
        const float4 w0 = lW4[k * 16 + g * 2 + 0];
        const float4 w1 = lW4[k * 16 + g * 2 + 1];
        a00.x = fmaf(v0, w0.x, a00.x); a00.y = fmaf(v0, w0.y, a00.y);
        a00.z = fmaf(v0, w0.z, a00.z); a00.w = fmaf(v0, w0.w, a00.w);
        a01.x = fmaf(v0, w1.x, a01.x); a01.y = fmaf(v0, w1.y, a01.y);
        a01.z = fmaf(v0, w1.z, a01.z); a01.w = fmaf(v0, w1.w, a01.w);
        a10.x = fmaf(v1, w0.x, a10.x); a10.y = fmaf(v1, w0.y, a10.y);
        a10.z = fmaf(v1, w0.z, a10.z); a10.w = fmaf(v1, w0.w, a10.w);
        a11.x = fmaf(v1, w1.x, a11.x); a11.y = fmaf(v1, w1.y, a11.y);
        a11.z = fmaf(v1, w1.z, a11.z); a11.w = fmaf(v1, w1.w, a11.w);
        a20.x = fmaf(v2, w0.x, a20.x); a20.y = fmaf(v2, w0.y, a20.y);
        a20.z = fmaf(v2, w0.z, a20.z); a20.w = fmaf(v2, w0.w, a20.w);
        a21.x = fmaf(v2, w1.x, a21.x); a21.y = fmaf(v2, w1.y, a21.y);
        a21.z = fmaf(v2, w1.z, a21.z); a21.w = fmaf(v2, w1.w, a21.w);
        a30.x = fmaf(v3, w0.x, a30.x); a30.y = fmaf(v3, w0.y, a30.y);
        a30.z = fmaf(v3, w0.z, a30.z); a30.w = fmaf(v3, w0.w, a30.w);
        a31.x = fmaf(v3, w1.x, a31.x); a31.y = fmaf(v3, w1.y, a31.y);
        a31.z = fmaf(v3, w1.z, a31.z); a31.w = fmaf(v3, w1.w, a31.w);
    }
    const float4 A0[4] = {a00, a10, a20, a30};
    const float4 A1[4] = {a01, a11, a21, a31};
    float4* o4 = (float4*)out;
    #pragma unroll
    for (int j = 0; j < 4; j++) {
        const int n = nbase + r0 + 32 * j;
        if (n < N_NODESC) {
            o4[(size_t)n * 16 + g * 2 + 0] = A0[j];
            o4[(size_t)n * 16 + g * 2 + 1] = A1[j];
        }
    }
}

// ---------------------------------------------------------------------------
extern "C" void kernel_launch(void* const* d_in, const int* in_sizes, int n_in,
                              void* d_out, int out_size, void* d_ws, size_t ws_size,
                              hipStream_t stream) {
    const float* x     = (const float*)d_in[0];
    const float* emb   = (const float*)d_in[1];
    const float* eps   = (const float*)d_in[2];
    const float* W1    = (const float*)d_in[3];
    const float* b1    = (const float*)d_in[4];
    const float* gamma = (const float*)d_in[5];
    const float* beta  = (const float*)d_in[6];
    const float* W2    = (const float*)d_in[7];
    const float* b2    = (const float*)d_in[8];
    const int*   ei    = (const int*)d_in[9];
    const int*   ea    = (const int*)d_in[10];
    float* out = (float*)d_out;

    // ws: [cs 64][css 64][Hm HN][Sloc HN][bsum 1024][tmp E][xh N*64 bf16]
    float* ws    = (float*)d_ws;
    float* cs    = ws;
    float* css   = ws + 64;
    int*   Hm    = (int*)(ws + 128);
    int*   Sloc  = Hm + HN;
    int*   bsum  = Sloc + HN;
    int*   tmp   = bsum + 1024;
    ushort* xh   = (ushort*)(tmp + N_EDGESC);

    k_hist_cast<<<SBLK, 1024, 0, stream>>>(ei, Hm, x, (uint2*)xh, cs);
    k_scan1<<<HN / 256, 256, 0, stream>>>(Hm, Sloc, bsum);
    k_scatter2<<<SBLK, 1024, 0, stream>>>(ei, ea, Sloc, bsum, tmp);
    k_aggf<<<782, 256, 0, stream>>>(xh, emb, bsum, tmp, out);

    const int nblk = (N_NODESC + MT - 1) / MT;   // 782
    k_mlp1<<<nblk, 256, 0, stream>>>(x, out, W1, b1, eps, cs, css);
    k_mlp2<<<nblk, 256, 0, stream>>>(out, W2, b2, gamma, beta, cs, css, out);
}